// Round 1
// baseline (318.104 us; speedup 1.0000x reference)
//
#include <hip/hip_runtime.h>
#include <stdint.h>

// ---------------------------------------------------------------------------
// Fused: Q=x@Wq^T+bq; K=y@Wk^T+bk; V=y@Wv^T+bv; ctx=softmax(QK^T/sqrt(384))@V
//        out = (x + ctx/||ctx||_row) @ Wo^T + bo        (N=M=8192, D=384)
// Math notes: softmax needs no max-subtraction here (logit sigma ~0.33), and
// the softmax denominator cancels under F.normalize -> never computed.
// ws layout (bytes), total ~75.5 MB:
//   Qb  bf16[8192,384]      @ 0
//   Kb  bf16[8192,384]      @ 6291456
//   Vt  bf16[384,8192]      @ 12582912   (V transposed: PV-friendly)
//   Xn  bf16[8192,384]      @ 18874368   (x + normalized ctx)
//   ctx f32 [4][8192,384]   @ 25165824   (per-KV-split numerators)
// ---------------------------------------------------------------------------

typedef __attribute__((ext_vector_type(8))) short bf16x8;
typedef __attribute__((ext_vector_type(4))) float f32x4;

#define DEV static __device__ __forceinline__

DEV short f2bf(float f) {
  uint32_t u = __builtin_bit_cast(uint32_t, f);
  u += 0x7fffu + ((u >> 16) & 1u);   // round-to-nearest-even
  return (short)(u >> 16);
}
DEV uint32_t pack2(float a, float b) {
  return (uint32_t)(uint16_t)f2bf(a) | ((uint32_t)(uint16_t)f2bf(b) << 16);
}

// ---------------------------------------------------------------------------
// Generic GEMM-NT: C[m,n] = sum_k A[m,k]*B[n,k] + bias   (MFMA bf16)
// A: f32 or bf16 row-major [M,K]; B: f32 row-major [N,K].
// BIAS_ON_N: bias[n] else bias[m]. OUT_F32: f32 else bf16 out.
// Tile 128x128, BK=64, 4 waves in 2x2 (64x64/wave). LDS XOR-swizzled (row&7)<<4.
// ---------------------------------------------------------------------------
template <int BIAS_ON_N, int OUT_F32, int A_F32>
__global__ __launch_bounds__(256) void gemm_nt(
    const void* __restrict__ Aptr, const float* __restrict__ B,
    const float* __restrict__ bias, void* __restrict__ Cptr,
    int M, int N, int K) {
  __shared__ char As[128 * 128];  // 128 rows x 64 bf16 = 128B/row
  __shared__ char Bs[128 * 128];
  const int tid = threadIdx.x;
  const int l = tid & 63, w = tid >> 6;
  const int lq = l & 15, lk = l >> 4;  // 0..15, 0..3
  const int m0 = blockIdx.x * 128, n0 = blockIdx.y * 128;
  const int wr = (w >> 1) * 64, wc = (w & 1) * 64;
  f32x4 acc[4][4] = {};

  for (int k0 = 0; k0 < K; k0 += 64) {
    // ---- stage A ----
    if (A_F32) {
      const float* A = (const float*)Aptr;
#pragma unroll
      for (int i = 0; i < 8; i++) {
        int c = tid + i * 256;            // 2048 chunks of 4 f32
        int row = c >> 4, col = (c & 15) * 4;
        f32x4 v = *(const f32x4*)(A + (size_t)(m0 + row) * K + k0 + col);
        uint32_t lo = pack2(v.x, v.y), hi = pack2(v.z, v.w);
        int off = (row * 128 + col * 2) ^ ((row & 7) << 4);
        *(uint32_t*)(As + off) = lo;
        *(uint32_t*)(As + off + 4) = hi;
      }
    } else {
      const short* A = (const short*)Aptr;
#pragma unroll
      for (int i = 0; i < 4; i++) {
        int c = tid + i * 256;            // 1024 chunks of 8 bf16
        int row = c >> 3, col = (c & 7) * 8;
        uint4 v = *(const uint4*)(A + (size_t)(m0 + row) * K + k0 + col);
        int off = (row * 128 + col * 2) ^ ((row & 7) << 4);
        *(uint4*)(As + off) = v;
      }
    }
    // ---- stage B (always f32 weights/acts) ----
#pragma unroll
    for (int i = 0; i < 8; i++) {
      int c = tid + i * 256;
      int row = c >> 4, col = (c & 15) * 4;
      f32x4 v = *(const f32x4*)(B + (size_t)(n0 + row) * K + k0 + col);
      uint32_t lo = pack2(v.x, v.y), hi = pack2(v.z, v.w);
      int off = (row * 128 + col * 2) ^ ((row & 7) << 4);
      *(uint32_t*)(Bs + off) = lo;
      *(uint32_t*)(Bs + off + 4) = hi;
    }
    __syncthreads();
#pragma unroll
    for (int ks = 0; ks < 2; ks++) {
      bf16x8 af[4], bfr[4];
#pragma unroll
      for (int m = 0; m < 4; m++) {
        int row = wr + m * 16 + lq;
        af[m] = *(const bf16x8*)(As + ((row * 128 + ks * 64 + lk * 16) ^ ((row & 7) << 4)));
      }
#pragma unroll
      for (int n = 0; n < 4; n++) {
        int row = wc + n * 16 + lq;
        bfr[n] = *(const bf16x8*)(Bs + ((row * 128 + ks * 64 + lk * 16) ^ ((row & 7) << 4)));
      }
#pragma unroll
      for (int m = 0; m < 4; m++)
#pragma unroll
        for (int n = 0; n < 4; n++)
          acc[m][n] = __builtin_amdgcn_mfma_f32_16x16x32_bf16(af[m], bfr[n], acc[m][n], 0, 0, 0);
    }
    __syncthreads();
  }
  // ---- epilogue: D frag (m = lk*4+r, n = lq) ----
#pragma unroll
  for (int m = 0; m < 4; m++) {
    int mg = m0 + wr + m * 16 + lk * 4;
#pragma unroll
    for (int n = 0; n < 4; n++) {
      int ng = n0 + wc + n * 16 + lq;
#pragma unroll
      for (int r = 0; r < 4; r++) {
        float v = acc[m][n][r] + (BIAS_ON_N ? bias[ng] : bias[mg + r]);
        if (OUT_F32)
          ((float*)Cptr)[(size_t)(mg + r) * N + ng] = v;
        else
          ((short*)Cptr)[(size_t)(mg + r) * N + ng] = f2bf(v);
      }
    }
  }
}

// ---------------------------------------------------------------------------
// Flash attention numerator: ctx_part[sp][q][d] = sum_{kv in split} exp2(S*c)*V
// Grid 512 = 128 q-tiles x 4 splits (split = blockIdx&3 -> XCD-aligned so each
// XCD L2 caches one 3.1MB K/V chunk). Block 256 thr / 4 waves, 16 q-rows/wave.
// Q frags live in registers (48 VGPR). 16x16x32 bf16 MFMA.
// LDS: K 32x768B XOR-swizzled, Vt 384x80B padded, P 64x80B padded = 60416 B.
// ---------------------------------------------------------------------------
#define FSPLIT 4
#define KVB 32
#define KVRANGE 2048  // 8192 / FSPLIT

__global__ __launch_bounds__(256, 2) void flash_attn(
    const short* __restrict__ Qb, const short* __restrict__ Kb,
    const short* __restrict__ Vt, float* __restrict__ ctx_part) {
  __shared__ char Ks[32 * 768];   // 24576
  __shared__ char Vs[384 * 80];   // 30720 (stride 40 bf16 breaks bank conflicts)
  __shared__ char Ps[64 * 80];    // 5120
  const int tid = threadIdx.x, l = tid & 63, w = tid >> 6;
  const int lq = l & 15, lk = l >> 4;
  const int sp = blockIdx.x & 3, qt = blockIdx.x >> 2;
  const int q0 = qt * 64 + w * 16;
  const float sc = 0.05103103630798288f * 1.4426950408889634f;  // (1/sqrt(384))*log2e

  // Q fragments: A-frag layout row=lq, k = ks*32 + lk*8 + j
  bf16x8 qf[12];
#pragma unroll
  for (int ks = 0; ks < 12; ks++)
    qf[ks] = *(const bf16x8*)(Qb + (size_t)(q0 + lq) * 384 + ks * 32 + lk * 8);

  f32x4 acc[24] = {};

  for (int t = 0; t < KVRANGE / KVB; t++) {
    const int kv0 = sp * KVRANGE + t * KVB;
    // ---- stage K tile [32 kv][384 k], swizzled ----
#pragma unroll
    for (int i = 0; i < 6; i++) {
      int c = tid + i * 256;              // 1536 chunks of 16B
      int row = c / 48, cb = (c % 48) * 16;
      uint4 v = *(const uint4*)((const char*)Kb + (size_t)(kv0 + row) * 768 + cb);
      *(uint4*)(Ks + ((row * 768 + cb) ^ ((row & 7) << 4))) = v;
    }
    // ---- stage Vt tile [384 d][32 kv], padded stride 80B ----
#pragma unroll
    for (int i = 0; i < 6; i++) {
      int c = tid + i * 256;
      int d = c >> 2, part = c & 3;
      uint4 v = *(const uint4*)((const char*)Vt + (size_t)d * 16384 + (size_t)(kv0 + part * 8) * 2);
      *(uint4*)(Vs + d * 80 + part * 16) = v;
    }
    __syncthreads();

    // ---- S = Q K^T  (per wave: [16 q] x [32 kv]); 4 accumulation chains ----
    f32x4 s0a = {}, s0b = {}, s1a = {}, s1b = {};
#pragma unroll
    for (int ks = 0; ks < 12; ks += 2) {
      int colb = ks * 64 + lk * 16;
      int r0 = lq, r1 = 16 + lq;
      bf16x8 b0 = *(const bf16x8*)(Ks + ((r0 * 768 + colb) ^ ((r0 & 7) << 4)));
      bf16x8 b1 = *(const bf16x8*)(Ks + ((r1 * 768 + colb) ^ ((r1 & 7) << 4)));
      bf16x8 b2 = *(const bf16x8*)(Ks + ((r0 * 768 + colb + 64) ^ ((r0 & 7) << 4)));
      bf16x8 b3 = *(const bf16x8*)(Ks + ((r1 * 768 + colb + 64) ^ ((r1 & 7) << 4)));
      s0a = __builtin_amdgcn_mfma_f32_16x16x32_bf16(qf[ks], b0, s0a, 0, 0, 0);
      s1a = __builtin_amdgcn_mfma_f32_16x16x32_bf16(qf[ks], b1, s1a, 0, 0, 0);
      s0b = __builtin_amdgcn_mfma_f32_16x16x32_bf16(qf[ks + 1], b2, s0b, 0, 0, 0);
      s1b = __builtin_amdgcn_mfma_f32_16x16x32_bf16(qf[ks + 1], b3, s1b, 0, 0, 0);
    }
    // ---- P = exp2(S*c) -> bf16 -> LDS (D frag: q = lk*4+r, kv = nf*16+lq) ----
#pragma unroll
    for (int r = 0; r < 4; r++) {
      int prow = w * 16 + lk * 4 + r;
      float p0 = exp2f((s0a[r] + s0b[r]) * sc);
      float p1 = exp2f((s1a[r] + s1b[r]) * sc);
      *(short*)(Ps + prow * 80 + lq * 2) = f2bf(p0);
      *(short*)(Ps + prow * 80 + 32 + lq * 2) = f2bf(p1);
    }
    asm volatile("s_waitcnt lgkmcnt(0)" ::: "memory");  // P writes visible wave-wide
    // ---- ctx += P @ V  (A = P[16,32] from LDS, B = Vt frags) ----
    bf16x8 pa = *(const bf16x8*)(Ps + (w * 16 + lq) * 80 + lk * 16);
#pragma unroll
    for (int nf = 0; nf < 24; nf++) {
      bf16x8 bv = *(const bf16x8*)(Vs + (nf * 16 + lq) * 80 + lk * 16);
      acc[nf] = __builtin_amdgcn_mfma_f32_16x16x32_bf16(pa, bv, acc[nf], 0, 0, 0);
    }
    __syncthreads();
  }
  // ---- epilogue: write split-numerator ----
  float* out = ctx_part + (size_t)sp * 8192 * 384;
#pragma unroll
  for (int nf = 0; nf < 24; nf++) {
    int d = nf * 16 + lq;
#pragma unroll
    for (int r = 0; r < 4; r++) {
      int q = q0 + lk * 4 + r;
      out[(size_t)q * 384 + d] = acc[nf][r];
    }
  }
}

// ---------------------------------------------------------------------------
// Combine: ctx = sum splits; Xn = bf16(x + ctx/max(||ctx||,eps)) ; eps moot
// (denominator L cancelled analytically). One wave per q row.
// ---------------------------------------------------------------------------
__global__ __launch_bounds__(256) void combine_norm(
    const float* __restrict__ ctx_part, const float* __restrict__ x,
    short* __restrict__ Xn) {
  const int l = threadIdx.x & 63, w = threadIdx.x >> 6;
  const int q = blockIdx.x * 4 + w;
  const size_t SLAB = (size_t)8192 * 384;
  float v[6];
  float ss = 0.f;
#pragma unroll
  for (int i = 0; i < 6; i++) {
    size_t off = (size_t)q * 384 + i * 64 + l;
    float s = ctx_part[off] + ctx_part[off + SLAB] + ctx_part[off + 2 * SLAB] +
              ctx_part[off + 3 * SLAB];
    v[i] = s;
    ss += s * s;
  }
#pragma unroll
  for (int m = 1; m <= 32; m <<= 1) ss += __shfl_xor(ss, m);
  float inv = 1.0f / fmaxf(sqrtf(ss), 1e-12f);
#pragma unroll
  for (int i = 0; i < 6; i++) {
    size_t off = (size_t)q * 384 + i * 64 + l;
    Xn[off] = f2bf(x[off] + v[i] * inv);
  }
}

// ---------------------------------------------------------------------------
extern "C" void kernel_launch(void* const* d_in, const int* in_sizes, int n_in,
                              void* d_out, int out_size, void* d_ws, size_t ws_size,
                              hipStream_t stream) {
  (void)in_sizes; (void)n_in; (void)out_size; (void)ws_size;
  const float* x  = (const float*)d_in[0];
  const float* y  = (const float*)d_in[1];
  const float* Wq = (const float*)d_in[2];
  const float* bq = (const float*)d_in[3];
  const float* Wk = (const float*)d_in[4];
  const float* bk = (const float*)d_in[5];
  const float* Wv = (const float*)d_in[6];
  const float* bv = (const float*)d_in[7];
  const float* Wo = (const float*)d_in[8];
  const float* bo = (const float*)d_in[9];

  char* ws = (char*)d_ws;
  short* Qb = (short*)(ws);
  short* Kb = (short*)(ws + 6291456);
  short* Vt = (short*)(ws + 12582912);
  short* Xn = (short*)(ws + 18874368);
  float* ctx = (float*)(ws + 25165824);  // 4 slabs f32 [8192,384]

  dim3 blk(256);
  // Q = x@Wq^T + bq ; K = y@Wk^T + bk   (bf16 out, bias on n)
  gemm_nt<1, 0, 1><<<dim3(64, 3), blk, 0, stream>>>(x, Wq, bq, Qb, 8192, 384, 384);
  gemm_nt<1, 0, 1><<<dim3(64, 3), blk, 0, stream>>>(y, Wk, bk, Kb, 8192, 384, 384);
  // Vt = (y@Wv^T + bv)^T directly: C[d,m] = sum_k Wv[d,k]*y[m,k] + bv[d]
  gemm_nt<0, 0, 1><<<dim3(3, 64), blk, 0, stream>>>(Wv, y, bv, Vt, 384, 8192, 384);
  // flash numerators (4 KV splits)
  flash_attn<<<dim3(512), blk, 0, stream>>>(Qb, Kb, Vt, ctx);
  // normalize + residual
  combine_norm<<<dim3(2048), blk, 0, stream>>>(ctx, x, Xn);
  // out = Xn@Wo^T + bo (f32 out)
  gemm_nt<1, 1, 0><<<dim3(64, 3), blk, 0, stream>>>(Xn, Wo, bo, (float*)d_out, 8192, 384, 384);
}